// Round 5
// baseline (199.170 us; speedup 1.0000x reference)
//
#include <hip/hip_runtime.h>
#include <hip/hip_bf16.h>

#define NB 4
#define CIN 128
#define NN 4096
#define DD 16
#define GG 4
#define EPSGN 1e-5f

typedef __attribute__((ext_vector_type(8))) short short8_t;
typedef __attribute__((ext_vector_type(4))) float f32x4;

// ---------------- workspace layout (float slots) ----------------
#define OFF_Q      0          // q f32 [b][n][16]       262144
#define OFF_T      262144     // t f32 [b][n][o]        262144
#define OFF_RINV   524288     // f32 [b][n]             16384
#define OFF_CINV   540672     // f32 [b][m]             16384
#define OFF_GN     557056     // f32 [b][g][2]          32
#define OFF_QB     557088     // bf16 [b][n][32] (d>=16 zero) -> 262144 slots
#define OFF_KB     819232     // bf16 [b][m][32]
#define OFF_VTB    1081376    // bf16 [b][d][4096]      131072 slots
// total 1212448 floats = 4.85 MB

static __device__ __forceinline__ int waveid() {
    return __builtin_amdgcn_readfirstlane((int)(threadIdx.x >> 6));
}
static __device__ __forceinline__ unsigned short f2bf(float x) {
    unsigned int u = __float_as_uint(x);
    u = (u + 0x7FFFu + ((u >> 16) & 1u)) >> 16;
    return (unsigned short)u;
}
static __device__ __forceinline__ unsigned int packbf(float a, float b) {
    return (unsigned int)f2bf(a) | ((unsigned int)f2bf(b) << 16);
}

// K1: 1x1 convs + positional terms -> q (f32), qb/kb (bf16, 32-padded),
// vtb (bf16 transposed [b][d][n]).  512 thr = 8 waves; lane <-> row,
// wave <-> 16-channel slice, 3-stage LDS tree.  Block 0 zeroes gnacc.
__global__ __launch_bounds__(512) void k_qkv(
    const float* __restrict__ x_q, const float* __restrict__ x_kv,
    const float* __restrict__ xyz_q, const float* __restrict__ xyz_kv,
    const float* __restrict__ w_qk, const float* __restrict__ w_v,
    const float* __restrict__ b_v, const float* __restrict__ w_pos_q,
    const float* __restrict__ w_pos_kv,
    float* __restrict__ q, unsigned short* __restrict__ qb,
    unsigned short* __restrict__ kb, unsigned short* __restrict__ vtb,
    float* __restrict__ gnacc)
{
    __shared__ float part[4][64][49];
    int lane = threadIdx.x & 63;
    int w = waveid();                  // 0..7
    int g0 = blockIdx.x * 64;          // b*NN + n base
    int b = g0 >> 12;
    int n = (g0 & (NN - 1)) + lane;

    if (blockIdx.x == 0 && threadIdx.x < 32) gnacc[threadIdx.x] = 0.f;

    const float* xq = x_q  + (size_t)b * CIN * NN + n;
    const float* xk = x_kv + (size_t)b * CIN * NN + n;

    float aq[DD], ak[DD], av[DD];
#pragma unroll
    for (int d = 0; d < DD; ++d) { aq[d] = 0.f; ak[d] = 0.f; av[d] = 0.f; }

    for (int ci = 0; ci < 16; ++ci) {
        int c = w * 16 + ci;
        float vq = xq[(size_t)c * NN];
        float vk = xk[(size_t)c * NN];
#pragma unroll
        for (int d = 0; d < DD; ++d) {
            float wq = w_qk[d * CIN + c];            // uniform -> scalar
            aq[d] = fmaf(wq, vq, aq[d]);
            ak[d] = fmaf(wq, vk, ak[d]);
            av[d] = fmaf(w_v[d * CIN + c], vk, av[d]);
        }
    }

    if (w >= 4) {
#pragma unroll
        for (int d = 0; d < DD; ++d) {
            part[w - 4][lane][d]      = aq[d];
            part[w - 4][lane][d + 16] = ak[d];
            part[w - 4][lane][d + 32] = av[d];
        }
    }
    __syncthreads();
    if (w < 4) {
#pragma unroll
        for (int d = 0; d < DD; ++d) {
            aq[d] += part[w][lane][d];
            ak[d] += part[w][lane][d + 16];
            av[d] += part[w][lane][d + 32];
        }
    }
    __syncthreads();
    if (w == 2 || w == 3) {
#pragma unroll
        for (int d = 0; d < DD; ++d) {
            part[w - 2][lane][d]      = aq[d];
            part[w - 2][lane][d + 16] = ak[d];
            part[w - 2][lane][d + 32] = av[d];
        }
    }
    __syncthreads();
    if (w < 2) {
#pragma unroll
        for (int d = 0; d < DD; ++d) {
            aq[d] += part[w][lane][d];
            ak[d] += part[w][lane][d + 16];
            av[d] += part[w][lane][d + 32];
        }
    }
    __syncthreads();
    if (w == 1) {
#pragma unroll
        for (int d = 0; d < DD; ++d) {
            part[0][lane][d]      = aq[d];
            part[0][lane][d + 16] = ak[d];
            part[0][lane][d + 32] = av[d];
        }
    }
    __syncthreads();
    if (w == 0) {
#pragma unroll
        for (int d = 0; d < DD; ++d) {
            aq[d] += part[0][lane][d];
            ak[d] += part[0][lane][d + 16];
            av[d] += part[0][lane][d + 32];
        }
        float pq0 = xyz_q[((size_t)b * 3 + 0) * NN + n];
        float pq1 = xyz_q[((size_t)b * 3 + 1) * NN + n];
        float pq2 = xyz_q[((size_t)b * 3 + 2) * NN + n];
        float pk0 = xyz_kv[((size_t)b * 3 + 0) * NN + n];
        float pk1 = xyz_kv[((size_t)b * 3 + 1) * NN + n];
        float pk2 = xyz_kv[((size_t)b * 3 + 2) * NN + n];
        size_t row = (size_t)g0 + lane;
        float qv[DD], kv[DD];
#pragma unroll
        for (int d = 0; d < DD; ++d) {
            float posq = w_pos_q[d * 3] * pq0 + w_pos_q[d * 3 + 1] * pq1 + w_pos_q[d * 3 + 2] * pq2;
            float posk = w_pos_kv[d * 3] * pk0 + w_pos_kv[d * 3 + 1] * pk1 + w_pos_kv[d * 3 + 2] * pk2;
            qv[d] = aq[d] + posq;
            kv[d] = ak[d] + posk;
            q[row * DD + d] = qv[d];
            vtb[((size_t)(b * DD + d)) * NN + n] = f2bf(av[d] + b_v[d] + posk);
        }
        unsigned int* qbw = (unsigned int*)(qb + row * 32);
        unsigned int* kbw = (unsigned int*)(kb + row * 32);
#pragma unroll
        for (int h = 0; h < 8; ++h) {
            qbw[h] = packbf(qv[2 * h], qv[2 * h + 1]);
            kbw[h] = packbf(kv[2 * h], kv[2 * h + 1]);
            qbw[h + 8] = 0u;                 // zero-pad d=16..31
            kbw[h + 8] = 0u;
        }
    }
}

// K2: rowinv via swapped MFMA: D[m,n] = K-tile x Q-tile^T; n lane-local.
// grid (NN/16, NB), block 256 (4 waves m-interleaved).
__global__ __launch_bounds__(256) void k_rows(
    const unsigned short* __restrict__ qb, const unsigned short* __restrict__ kb,
    float* __restrict__ rowinv)
{
    __shared__ float red[4][16];
    int lane = threadIdx.x & 63;
    int w = waveid();
    int j = lane & 15, g = lane >> 4;
    int b = blockIdx.y;
    int n0 = blockIdx.x * 16;

    short8_t qf = *reinterpret_cast<const short8_t*>(qb + ((size_t)(b * NN + n0 + j)) * 32 + 8 * g);
    const unsigned short* kbb = kb + (size_t)b * NN * 32;

    float rs = 0.f;
#pragma unroll 2
    for (int mt = w; mt < 256; mt += 4) {
        short8_t kf = *reinterpret_cast<const short8_t*>(kbb + ((size_t)(mt * 16 + j)) * 32 + 8 * g);
        f32x4 c = __builtin_amdgcn_mfma_f32_16x16x32_bf16(kf, qf, (f32x4){0.f, 0.f, 0.f, 0.f}, 0, 0, 0);
        rs += __expf(c[0]) + __expf(c[1]) + __expf(c[2]) + __expf(c[3]);
    }
    rs += __shfl_xor(rs, 16);
    rs += __shfl_xor(rs, 32);
    if (lane < 16) red[w][lane] = rs;
    __syncthreads();
    if (threadIdx.x < 16)
        rowinv[(size_t)b * NN + n0 + threadIdx.x] =
            1.0f / (red[0][threadIdx.x] + red[1][threadIdx.x] + red[2][threadIdx.x] + red[3][threadIdx.x]);
}

// K3: colinv via non-swapped MFMA: D[n,m] = Q-tile x K-tile^T; m lane-local.
// rinv staged in LDS. grid (NN/16, NB), block 256.
__global__ __launch_bounds__(256) void k_cols(
    const unsigned short* __restrict__ qb, const unsigned short* __restrict__ kb,
    const float* __restrict__ rowinv, float* __restrict__ colinv)
{
    __shared__ float ri_l[NN];
    __shared__ float red[4][16];
    int lane = threadIdx.x & 63;
    int w = waveid();
    int j = lane & 15, g = lane >> 4;
    int b = blockIdx.y;
    int m0 = blockIdx.x * 16;

    {   // coalesced stage of rowinv[b][:]
        const float4* src = (const float4*)(rowinv + (size_t)b * NN);
        float4* dst = (float4*)ri_l;
        for (int i = threadIdx.x; i < NN / 4; i += 256) dst[i] = src[i];
    }
    short8_t kf = *reinterpret_cast<const short8_t*>(kb + ((size_t)(b * NN + m0 + j)) * 32 + 8 * g);
    const unsigned short* qbb = qb + (size_t)b * NN * 32;
    __syncthreads();

    float cs = 0.f;
#pragma unroll 2
    for (int nt = w; nt < 256; nt += 4) {
        short8_t qf = *reinterpret_cast<const short8_t*>(qbb + ((size_t)(nt * 16 + j)) * 32 + 8 * g);
        f32x4 c = __builtin_amdgcn_mfma_f32_16x16x32_bf16(qf, kf, (f32x4){0.f, 0.f, 0.f, 0.f}, 0, 0, 0);
        const float4 rv = *reinterpret_cast<const float4*>(&ri_l[nt * 16 + 4 * g]);
        cs += __expf(c[0]) * rv.x + __expf(c[1]) * rv.y + __expf(c[2]) * rv.z + __expf(c[3]) * rv.w;
    }
    cs += __shfl_xor(cs, 16);
    cs += __shfl_xor(cs, 32);
    if (lane < 16) red[w][lane] = cs;
    __syncthreads();
    if (threadIdx.x < 16)
        colinv[(size_t)b * NN + m0 + threadIdx.x] =
            1.0f / (1e-9f + red[0][threadIdx.x] + red[1][threadIdx.x] + red[2][threadIdx.x] + red[3][threadIdx.x]);
}

// K4: xr (in-register) + t + GN partials.  Per 32-m chunk: two swapped QK
// tiles -> P' = exp*rinv[n]*colinv[m] -> bf16 repack (LDS) -> PV mfma with
// vtb.  4-wave LDS combine; wave0 computes t = w_t*(q-xr)+b_t, writes t,
// accumulates per-(b,group) sum/sumsq atomics.  grid (NN/16, NB), 256 thr.
__global__ __launch_bounds__(256) void k_xr(
    const unsigned short* __restrict__ qb, const unsigned short* __restrict__ kb,
    const unsigned short* __restrict__ vtb, const float* __restrict__ rowinv,
    const float* __restrict__ colinv, const float* __restrict__ q,
    const float* __restrict__ w_t, const float* __restrict__ b_t,
    float* __restrict__ t, float* __restrict__ gnacc)
{
    __shared__ __align__(16) unsigned int plds_all[4][320]; // per-wave [16 n][pitch 20 uints]
    __shared__ float xls[4][64][4];
    __shared__ float pt[4][17][16];                          // [gg][o(pad)][j]
    int lane = threadIdx.x & 63;
    int w = waveid();
    int j = lane & 15, g = lane >> 4;
    int b = blockIdx.y;
    int n0 = blockIdx.x * 16;
    unsigned int* plds = plds_all[w];

    short8_t qf = *reinterpret_cast<const short8_t*>(qb + ((size_t)(b * NN + n0 + j)) * 32 + 8 * g);
    float ri = rowinv[(size_t)b * NN + n0 + j];
    const unsigned short* kbb  = kb  + (size_t)b * NN * 32;
    const unsigned short* vtbb = vtb + (size_t)b * DD * NN;
    const float* civ = colinv + (size_t)b * NN;

    f32x4 acc = {0.f, 0.f, 0.f, 0.f};
    for (int MC = w; MC < 128; MC += 4) {       // 32-wide m chunk
        int M = MC * 32;
        short8_t kf0 = *reinterpret_cast<const short8_t*>(kbb + ((size_t)(M + j)) * 32 + 8 * g);
        short8_t kf1 = *reinterpret_cast<const short8_t*>(kbb + ((size_t)(M + 16 + j)) * 32 + 8 * g);
        f32x4 c0 = __builtin_amdgcn_mfma_f32_16x16x32_bf16(kf0, qf, (f32x4){0.f, 0.f, 0.f, 0.f}, 0, 0, 0);
        f32x4 c1 = __builtin_amdgcn_mfma_f32_16x16x32_bf16(kf1, qf, (f32x4){0.f, 0.f, 0.f, 0.f}, 0, 0, 0);
        const float4 civ0 = *reinterpret_cast<const float4*>(civ + M + 4 * g);
        const float4 civ1 = *reinterpret_cast<const float4*>(civ + M + 16 + 4 * g);
        // lane holds rows m = 4g+r (tile0), 16+4g+r (tile1), col n = j
        float p00 = __expf(c0[0]) * ri * civ0.x, p01 = __expf(c0[1]) * ri * civ0.y;
        float p02 = __expf(c0[2]) * ri * civ0.z, p03 = __expf(c0[3]) * ri * civ0.w;
        float p10 = __expf(c1[0]) * ri * civ1.x, p11 = __expf(c1[1]) * ri * civ1.y;
        float p12 = __expf(c1[2]) * ri * civ1.z, p13 = __expf(c1[3]) * ri * civ1.w;
        // repack: P_lds[n=j][m] bf16, pitch 40 bf16 (20 uints)
        int base = j * 20;
        plds[base + 2 * g]         = packbf(p00, p01);
        plds[base + 2 * g + 1]     = packbf(p02, p03);
        plds[base + 8 + 2 * g]     = packbf(p10, p11);
        plds[base + 8 + 2 * g + 1] = packbf(p12, p13);
        // B-frag read: lane (g,j): n=j, m = 8g..8g+7 (16B aligned)
        short8_t pf = *reinterpret_cast<const short8_t*>(&plds[base + 4 * g]);
        // A-frag: v^T: lane: d = j, m = M + 8g..+7
        short8_t vf = *reinterpret_cast<const short8_t*>(vtbb + ((size_t)j) * NN + M + 8 * g);
        acc = __builtin_amdgcn_mfma_f32_16x16x32_bf16(vf, pf, acc, 0, 0, 0);
    }
#pragma unroll
    for (int r = 0; r < 4; ++r) xls[w][lane][r] = acc[r];
    __syncthreads();
    if (w == 0) {
        // lane (g,j): xr[n0+j][4g..4g+3]
        float4 tot;
        tot.x = xls[0][lane][0] + xls[1][lane][0] + xls[2][lane][0] + xls[3][lane][0];
        tot.y = xls[0][lane][1] + xls[1][lane][1] + xls[2][lane][1] + xls[3][lane][1];
        tot.z = xls[0][lane][2] + xls[1][lane][2] + xls[2][lane][2] + xls[3][lane][2];
        tot.w = xls[0][lane][3] + xls[1][lane][3] + xls[2][lane][3] + xls[3][lane][3];
        size_t row = (size_t)b * NN + n0 + j;
        const float4 q4 = *reinterpret_cast<const float4*>(q + row * DD + 4 * g);
        float d0 = q4.x - tot.x, d1 = q4.y - tot.y, d2 = q4.z - tot.z, d3 = q4.w - tot.w;
        // partial matvec over this lane's d-quad, all 16 o -> LDS [g][o][j]
#pragma unroll
        for (int o = 0; o < DD; ++o) {
            const float4 wt = *reinterpret_cast<const float4*>(w_t + o * DD + 4 * g);
            pt[g][o][j] = wt.x * d0 + wt.y * d1 + wt.z * d2 + wt.w * d3;
        }
        __builtin_amdgcn_s_waitcnt(0);   // lgkmcnt(0): same-wave LDS ordering
        // lane (g,j) gathers its o-quad (o = 4g..4g+3), adds bias
        const float4 bt4 = *reinterpret_cast<const float4*>(b_t + 4 * g);
        float tq[4];
#pragma unroll
        for (int i = 0; i < 4; ++i) {
            int o = 4 * g + i;                    // runtime LDS index: fine
            tq[i] = pt[0][o][j] + pt[1][o][j] + pt[2][o][j] + pt[3][o][j];
        }
        tq[0] += bt4.x; tq[1] += bt4.y; tq[2] += bt4.z; tq[3] += bt4.w;
        float4 tout = {tq[0], tq[1], tq[2], tq[3]};
        *reinterpret_cast<float4*>(t + row * DD + 4 * g) = tout;
        // GN partials: this lane's quad == group g of row n0+j
        float s  = tq[0] + tq[1] + tq[2] + tq[3];
        float sq = tq[0]*tq[0] + tq[1]*tq[1] + tq[2]*tq[2] + tq[3]*tq[3];
#pragma unroll
        for (int dlt = 1; dlt < 16; dlt <<= 1) {
            s  += __shfl_xor(s, dlt);
            sq += __shfl_xor(sq, dlt);
        }
        if (j == 0) {
            atomicAdd(&gnacc[(b * GG + g) * 2 + 0], s);
            atomicAdd(&gnacc[(b * GG + g) * 2 + 1], sq);
        }
    }
}

// K5: out = q + relu(gn(t)), LDS-transposed stores. grid NB*NN/64 = 256 blocks.
__global__ __launch_bounds__(256) void k_out(
    const float* __restrict__ q, const float* __restrict__ t,
    const float* __restrict__ gnacc, const float* __restrict__ gamma,
    const float* __restrict__ beta, float* __restrict__ out)
{
    __shared__ float tl[64][17], ql[64][17];
    int tid = threadIdx.x;
    int g0 = blockIdx.x * 64;          // row base (b*NN + n)
    int b = g0 >> 12;

    {
        float4 tv = *reinterpret_cast<const float4*>(t + (size_t)g0 * DD + tid * 4);
        float4 qv = *reinterpret_cast<const float4*>(q + (size_t)g0 * DD + tid * 4);
        int r = (tid * 4) >> 4, c = (tid * 4) & 15;
        tl[r][c] = tv.x; tl[r][c + 1] = tv.y; tl[r][c + 2] = tv.z; tl[r][c + 3] = tv.w;
        ql[r][c] = qv.x; ql[r][c + 1] = qv.y; ql[r][c + 2] = qv.z; ql[r][c + 3] = qv.w;
    }
    __syncthreads();

    int o = tid >> 4, n16 = tid & 15;
    int g = o >> 2;
    const float cnt = 1.0f / (4.0f * NN);
    float ms = gnacc[(b * GG + g) * 2 + 0];
    float sqs = gnacc[(b * GG + g) * 2 + 1];
    float mean = ms * cnt;
    float var = sqs * cnt - mean * mean;
    float rsig = rsqrtf(var + EPSGN);
    float ga = gamma[o], be = beta[o];

    int r0 = n16 * 4;
    float4 res;
    res.x = ql[r0    ][o] + fmaxf((tl[r0    ][o] - mean) * rsig * ga + be, 0.f);
    res.y = ql[r0 + 1][o] + fmaxf((tl[r0 + 1][o] - mean) * rsig * ga + be, 0.f);
    res.z = ql[r0 + 2][o] + fmaxf((tl[r0 + 2][o] - mean) * rsig * ga + be, 0.f);
    res.w = ql[r0 + 3][o] + fmaxf((tl[r0 + 3][o] - mean) * rsig * ga + be, 0.f);
    *reinterpret_cast<float4*>(out + ((size_t)(b * DD + o)) * NN + (g0 & (NN - 1)) + r0) = res;
}

extern "C" void kernel_launch(void* const* d_in, const int* in_sizes, int n_in,
                              void* d_out, int out_size, void* d_ws, size_t ws_size,
                              hipStream_t stream)
{
    const float* x_q      = (const float*)d_in[0];
    const float* x_kv     = (const float*)d_in[1];
    const float* xyz_q    = (const float*)d_in[2];
    const float* xyz_kv   = (const float*)d_in[3];
    const float* w_qk     = (const float*)d_in[4];
    const float* w_v      = (const float*)d_in[5];
    const float* b_v      = (const float*)d_in[6];
    const float* w_t      = (const float*)d_in[7];
    const float* b_t      = (const float*)d_in[8];
    const float* gamma    = (const float*)d_in[9];
    const float* beta     = (const float*)d_in[10];
    const float* w_pos_q  = (const float*)d_in[11];
    const float* w_pos_kv = (const float*)d_in[12];

    float* ws = (float*)d_ws;
    float* q       = ws + OFF_Q;
    float* t       = ws + OFF_T;
    float* rowinv  = ws + OFF_RINV;
    float* colinv  = ws + OFF_CINV;
    float* gnacc   = ws + OFF_GN;
    unsigned short* qb  = (unsigned short*)(ws + OFF_QB);
    unsigned short* kb  = (unsigned short*)(ws + OFF_KB);
    unsigned short* vtb = (unsigned short*)(ws + OFF_VTB);
    float* out     = (float*)d_out;

    k_qkv<<<dim3(NB * NN / 64), 512, 0, stream>>>(
        x_q, x_kv, xyz_q, xyz_kv, w_qk, w_v, b_v, w_pos_q, w_pos_kv,
        q, qb, kb, vtb, gnacc);

    dim3 gt(NN / 16, NB);
    k_rows<<<gt, 256, 0, stream>>>(qb, kb, rowinv);
    k_cols<<<gt, 256, 0, stream>>>(qb, kb, rowinv, colinv);
    k_xr<<<gt, 256, 0, stream>>>(qb, kb, vtb, rowinv, colinv, q, w_t, b_t, t, gnacc);
    k_out<<<dim3(NB * NN / 64), 256, 0, stream>>>(q, t, gnacc, gamma, beta, out);
}

// Round 7
// 178.421 us; speedup vs baseline: 1.1163x; 1.1163x over previous
//
#include <hip/hip_runtime.h>
#include <hip/hip_bf16.h>

#define NB 4
#define CIN 128
#define NN 4096
#define DD 16
#define GG 4
#define EPSGN 1e-5f

typedef __attribute__((ext_vector_type(8))) short short8_t;
typedef __attribute__((ext_vector_type(4))) float f32x4;
typedef __attribute__((ext_vector_type(16))) float f32x16;

// ---------------- workspace layout (float slots) ----------------
#define OFF_Q      0          // q f32 [b][n][16]       262144
#define OFF_T      262144     // t f32 [b][n][o]        262144
#define OFF_GN     524288     // f32 [b][g][2]          32 (pad to 524320)
#define OFF_QB     524320     // bf16 [b][n][32]: d0..15 = q, 16..17 = lri hi/lo, 18..19 = 1,1
#define OFF_KB     786464     // bf16 [b][m][32]: d0..15 = k, 16..17 = 1,1,  18..19 = lci hi/lo
#define OFF_VTB    1048608    // bf16 [b][d][4096]      131072 slots
// total 1179680 floats = 4.72 MB

static __device__ __forceinline__ int waveid() {
    return __builtin_amdgcn_readfirstlane((int)(threadIdx.x >> 6));
}
static __device__ __forceinline__ unsigned int bfpk(float a, float b) {
    union { __hip_bfloat162 h2; unsigned int u; } c;
    c.h2 = __float22bfloat162_rn(float2{a, b});
    return c.u;
}
static __device__ __forceinline__ unsigned short bf1(float a) {
    union { __hip_bfloat16 h1; unsigned short u; } c;
    c.h1 = __float2bfloat16(a);
    return c.u;
}

// K1: 1x1 convs + positional terms -> q (f32), qb/kb (bf16, padded per layout),
// vtb (bf16 transposed [b][d][n]).  512 thr = 8 waves; lane <-> row,
// wave <-> 16-channel slice, 3-stage LDS tree.  Block 0 zeroes gnacc.
__global__ __launch_bounds__(512) void k_qkv(
    const float* __restrict__ x_q, const float* __restrict__ x_kv,
    const float* __restrict__ xyz_q, const float* __restrict__ xyz_kv,
    const float* __restrict__ w_qk, const float* __restrict__ w_v,
    const float* __restrict__ b_v, const float* __restrict__ w_pos_q,
    const float* __restrict__ w_pos_kv,
    float* __restrict__ q, unsigned short* __restrict__ qb,
    unsigned short* __restrict__ kb, unsigned short* __restrict__ vtb,
    float* __restrict__ gnacc)
{
    __shared__ float part[4][64][49];
    int lane = threadIdx.x & 63;
    int w = waveid();                  // 0..7
    int g0 = blockIdx.x * 64;          // b*NN + n base
    int b = g0 >> 12;
    int n = (g0 & (NN - 1)) + lane;

    if (blockIdx.x == 0 && threadIdx.x < 32) gnacc[threadIdx.x] = 0.f;

    const float* xq = x_q  + (size_t)b * CIN * NN + n;
    const float* xk = x_kv + (size_t)b * CIN * NN + n;

    float aq[DD], ak[DD], av[DD];
#pragma unroll
    for (int d = 0; d < DD; ++d) { aq[d] = 0.f; ak[d] = 0.f; av[d] = 0.f; }

    for (int ci = 0; ci < 16; ++ci) {
        int c = w * 16 + ci;
        float vq = xq[(size_t)c * NN];
        float vk = xk[(size_t)c * NN];
#pragma unroll
        for (int d = 0; d < DD; ++d) {
            float wq = w_qk[d * CIN + c];            // uniform -> scalar
            aq[d] = fmaf(wq, vq, aq[d]);
            ak[d] = fmaf(wq, vk, ak[d]);
            av[d] = fmaf(w_v[d * CIN + c], vk, av[d]);
        }
    }

    if (w >= 4) {
#pragma unroll
        for (int d = 0; d < DD; ++d) {
            part[w - 4][lane][d]      = aq[d];
            part[w - 4][lane][d + 16] = ak[d];
            part[w - 4][lane][d + 32] = av[d];
        }
    }
    __syncthreads();
    if (w < 4) {
#pragma unroll
        for (int d = 0; d < DD; ++d) {
            aq[d] += part[w][lane][d];
            ak[d] += part[w][lane][d + 16];
            av[d] += part[w][lane][d + 32];
        }
    }
    __syncthreads();
    if (w == 2 || w == 3) {
#pragma unroll
        for (int d = 0; d < DD; ++d) {
            part[w - 2][lane][d]      = aq[d];
            part[w - 2][lane][d + 16] = ak[d];
            part[w - 2][lane][d + 32] = av[d];
        }
    }
    __syncthreads();
    if (w < 2) {
#pragma unroll
        for (int d = 0; d < DD; ++d) {
            aq[d] += part[w][lane][d];
            ak[d] += part[w][lane][d + 16];
            av[d] += part[w][lane][d + 32];
        }
    }
    __syncthreads();
    if (w == 1) {
#pragma unroll
        for (int d = 0; d < DD; ++d) {
            part[0][lane][d]      = aq[d];
            part[0][lane][d + 16] = ak[d];
            part[0][lane][d + 32] = av[d];
        }
    }
    __syncthreads();
    if (w == 0) {
#pragma unroll
        for (int d = 0; d < DD; ++d) {
            aq[d] += part[0][lane][d];
            ak[d] += part[0][lane][d + 16];
            av[d] += part[0][lane][d + 32];
        }
        float pq0 = xyz_q[((size_t)b * 3 + 0) * NN + n];
        float pq1 = xyz_q[((size_t)b * 3 + 1) * NN + n];
        float pq2 = xyz_q[((size_t)b * 3 + 2) * NN + n];
        float pk0 = xyz_kv[((size_t)b * 3 + 0) * NN + n];
        float pk1 = xyz_kv[((size_t)b * 3 + 1) * NN + n];
        float pk2 = xyz_kv[((size_t)b * 3 + 2) * NN + n];
        size_t row = (size_t)g0 + lane;
        float qv[DD], kv[DD];
#pragma unroll
        for (int d = 0; d < DD; ++d) {
            float posq = w_pos_q[d * 3] * pq0 + w_pos_q[d * 3 + 1] * pq1 + w_pos_q[d * 3 + 2] * pq2;
            float posk = w_pos_kv[d * 3] * pk0 + w_pos_kv[d * 3 + 1] * pk1 + w_pos_kv[d * 3 + 2] * pk2;
            qv[d] = aq[d] + posq;
            kv[d] = ak[d] + posk;
            q[row * DD + d] = qv[d];
            vtb[((size_t)(b * DD + d)) * NN + n] = bf1(av[d] + b_v[d] + posk);
        }
        unsigned int* qbw = (unsigned int*)(qb + row * 32);
        unsigned int* kbw = (unsigned int*)(kb + row * 32);
#pragma unroll
        for (int h = 0; h < 8; ++h) {
            qbw[h] = bfpk(qv[2 * h], qv[2 * h + 1]);
            kbw[h] = bfpk(kv[2 * h], kv[2 * h + 1]);
        }
        qbw[8] = 0u;                 // lri slot (k_rows writes)
        qbw[9] = bfpk(1.f, 1.f);     // picks up lci from kb[18..19]
        kbw[8] = bfpk(1.f, 1.f);     // picks up lri from qb[16..17]
        kbw[9] = 0u;                 // lci slot (k_cols writes)
#pragma unroll
        for (int h = 10; h < 16; ++h) { qbw[h] = 0u; kbw[h] = 0u; }
    }
}

// K2: rowsum via swapped 32x32x16 MFMA (K=16, pads not read): D[m,n], n=lane&31.
// Writes lri = -log(rowsum) as bf16 hi/lo into qb[n][16..17].
// grid (NN/32, NB), block 512 (8 waves, m-interleaved).
__global__ __launch_bounds__(512) void k_rows(
    unsigned short* __restrict__ qb, const unsigned short* __restrict__ kb)
{
    __shared__ float red[8][32];
    int lane = threadIdx.x & 63;
    int w = waveid();
    int l31 = lane & 31, h = lane >> 5;
    int b = blockIdx.y;
    int n0 = blockIdx.x * 32;

    unsigned short* qbb = qb + (size_t)b * NN * 32;
    const unsigned short* kbb = kb + (size_t)b * NN * 32;
    short8_t qf = *reinterpret_cast<const short8_t*>(qbb + (n0 + l31) * 32 + 8 * h);

    const f32x16 z16 = {0.f,0.f,0.f,0.f,0.f,0.f,0.f,0.f,0.f,0.f,0.f,0.f,0.f,0.f,0.f,0.f};
    float rs = 0.f;
#pragma unroll 2
    for (int mt = w; mt < 128; mt += 8) {
        short8_t kf = *reinterpret_cast<const short8_t*>(kbb + (mt * 32 + l31) * 32 + 8 * h);
        f32x16 c = __builtin_amdgcn_mfma_f32_32x32x16_bf16(kf, qf, z16, 0, 0, 0);
#pragma unroll
        for (int r = 0; r < 16; ++r) rs += __expf(c[r]);
    }
    rs += __shfl_xor(rs, 32);
    if (lane < 32) red[w][l31] = rs;
    __syncthreads();
    if (threadIdx.x < 32) {
        float s = 0.f;
#pragma unroll
        for (int ww = 0; ww < 8; ++ww) s += red[ww][threadIdx.x];
        float lri = -__logf(s);
        float hi = __bfloat162float(__float2bfloat16(lri));
        *(unsigned int*)(qbb + (n0 + threadIdx.x) * 32 + 16) = bfpk(lri, lri - hi);
    }
}

// K3: colsum via non-swapped 16x16x32 MFMA with K=32 incl. pads:
// e' = e + lri[n] (qb pads x kb[16..17]=1).  cs = sum_n exp(e').
// Writes lci = -log(1e-9+cs) bf16 hi/lo into kb[m][18..19].
// grid (NN/16, NB), block 256 (4 waves, n-interleaved).
__global__ __launch_bounds__(256) void k_cols(
    const unsigned short* __restrict__ qb, unsigned short* __restrict__ kb)
{
    __shared__ float red[4][16];
    int lane = threadIdx.x & 63;
    int w = waveid();
    int j = lane & 15, g = lane >> 4;
    int b = blockIdx.y;
    int m0 = blockIdx.x * 16;

    unsigned short* kbb = kb + (size_t)b * NN * 32;
    const unsigned short* qbb = qb + (size_t)b * NN * 32;
    short8_t kf = *reinterpret_cast<const short8_t*>(kbb + (m0 + j) * 32 + 8 * g);

    float cs = 0.f;
#pragma unroll 2
    for (int nt = w; nt < 256; nt += 4) {
        short8_t qf = *reinterpret_cast<const short8_t*>(qbb + (nt * 16 + j) * 32 + 8 * g);
        f32x4 c = __builtin_amdgcn_mfma_f32_16x16x32_bf16(qf, kf, (f32x4){0.f, 0.f, 0.f, 0.f}, 0, 0, 0);
        cs += __expf(c[0]) + __expf(c[1]) + __expf(c[2]) + __expf(c[3]);
    }
    cs += __shfl_xor(cs, 16);
    cs += __shfl_xor(cs, 32);
    if (lane < 16) red[w][lane] = cs;
    __syncthreads();
    if (threadIdx.x < 16) {
        float s = red[0][threadIdx.x] + red[1][threadIdx.x] + red[2][threadIdx.x] + red[3][threadIdx.x];
        float lci = -__logf(1e-9f + s);
        float hi = __bfloat162float(__float2bfloat16(lci));
        *(unsigned int*)(kbb + (m0 + threadIdx.x) * 32 + 18) = bfpk(lci, lci - hi);
    }
}

// K4 helper: one 32-m chunk of the xr pass.  e' = e + lri + lci via pads,
// P = exp(e') -> bf16 repack (LDS) -> PV mfma accumulate.
static __device__ __forceinline__ void xr_body(
    int M, unsigned int* __restrict__ plds,
    const unsigned short* __restrict__ kbb, const unsigned short* __restrict__ vtbb,
    short8_t qf, int j, int g, f32x4& acc)
{
    short8_t kf0 = *reinterpret_cast<const short8_t*>(kbb + (M + j) * 32 + 8 * g);
    short8_t kf1 = *reinterpret_cast<const short8_t*>(kbb + (M + 16 + j) * 32 + 8 * g);
    f32x4 c0 = __builtin_amdgcn_mfma_f32_16x16x32_bf16(kf0, qf, (f32x4){0.f, 0.f, 0.f, 0.f}, 0, 0, 0);
    f32x4 c1 = __builtin_amdgcn_mfma_f32_16x16x32_bf16(kf1, qf, (f32x4){0.f, 0.f, 0.f, 0.f}, 0, 0, 0);
    float p00 = __expf(c0[0]), p01 = __expf(c0[1]), p02 = __expf(c0[2]), p03 = __expf(c0[3]);
    float p10 = __expf(c1[0]), p11 = __expf(c1[1]), p12 = __expf(c1[2]), p13 = __expf(c1[3]);
    int base = j * 20;
    plds[base + 2 * g]         = bfpk(p00, p01);
    plds[base + 2 * g + 1]     = bfpk(p02, p03);
    plds[base + 8 + 2 * g]     = bfpk(p10, p11);
    plds[base + 8 + 2 * g + 1] = bfpk(p12, p13);
    short8_t pf = *reinterpret_cast<const short8_t*>(&plds[base + 4 * g]);
    short8_t vf = *reinterpret_cast<const short8_t*>(vtbb + j * NN + M + 8 * g);
    acc = __builtin_amdgcn_mfma_f32_16x16x32_bf16(vf, pf, acc, 0, 0, 0);
}

// K4: xr + t + GN partials.  grid (NN/16, NB), 256 thr (4 waves, m-split),
// unroll-2 with dual plds buffers; padded scalar xls combine (2-way banks).
__global__ __launch_bounds__(256) void k_xr(
    const unsigned short* __restrict__ qb, const unsigned short* __restrict__ kb,
    const unsigned short* __restrict__ vtb, const float* __restrict__ q,
    const float* __restrict__ w_t, const float* __restrict__ b_t,
    float* __restrict__ t, float* __restrict__ gnacc)
{
    __shared__ __align__(16) unsigned int plds_all[4][2][320];
    __shared__ float xls[4][64][5];
    __shared__ float pt[4][17][16];
    int lane = threadIdx.x & 63;
    int w = waveid();
    int j = lane & 15, g = lane >> 4;
    int b = blockIdx.y;
    int n0 = blockIdx.x * 16;

    short8_t qf = *reinterpret_cast<const short8_t*>(qb + ((size_t)(b * NN + n0 + j)) * 32 + 8 * g);
    const unsigned short* kbb  = kb  + (size_t)b * NN * 32;
    const unsigned short* vtbb = vtb + (size_t)b * DD * NN;
    unsigned int* plds0 = plds_all[w][0];
    unsigned int* plds1 = plds_all[w][1];

    f32x4 acc = {0.f, 0.f, 0.f, 0.f};
    for (int MC = w; MC < 128; MC += 8) {
        xr_body(MC * 32,       plds0, kbb, vtbb, qf, j, g, acc);
        xr_body(MC * 32 + 128, plds1, kbb, vtbb, qf, j, g, acc);
    }
#pragma unroll
    for (int r = 0; r < 4; ++r) xls[w][lane][r] = acc[r];
    __syncthreads();
    if (w == 0) {
        float4 tot;
        tot.x = xls[0][lane][0] + xls[1][lane][0] + xls[2][lane][0] + xls[3][lane][0];
        tot.y = xls[0][lane][1] + xls[1][lane][1] + xls[2][lane][1] + xls[3][lane][1];
        tot.z = xls[0][lane][2] + xls[1][lane][2] + xls[2][lane][2] + xls[3][lane][2];
        tot.w = xls[0][lane][3] + xls[1][lane][3] + xls[2][lane][3] + xls[3][lane][3];
        size_t row = (size_t)b * NN + n0 + j;
        const float4 q4 = *reinterpret_cast<const float4*>(q + row * DD + 4 * g);
        float d0 = q4.x - tot.x, d1 = q4.y - tot.y, d2 = q4.z - tot.z, d3 = q4.w - tot.w;
#pragma unroll
        for (int o = 0; o < DD; ++o) {
            const float4 wt = *reinterpret_cast<const float4*>(w_t + o * DD + 4 * g);
            pt[g][o][j] = wt.x * d0 + wt.y * d1 + wt.z * d2 + wt.w * d3;
        }
        __builtin_amdgcn_s_waitcnt(0);   // lgkmcnt(0): same-wave LDS ordering
        const float4 bt4 = *reinterpret_cast<const float4*>(b_t + 4 * g);
        float tq[4];
#pragma unroll
        for (int i = 0; i < 4; ++i) {
            int o = 4 * g + i;
            tq[i] = pt[0][o][j] + pt[1][o][j] + pt[2][o][j] + pt[3][o][j];
        }
        tq[0] += bt4.x; tq[1] += bt4.y; tq[2] += bt4.z; tq[3] += bt4.w;
        float4 tout = {tq[0], tq[1], tq[2], tq[3]};
        *reinterpret_cast<float4*>(t + row * DD + 4 * g) = tout;
        float s  = tq[0] + tq[1] + tq[2] + tq[3];
        float sq = tq[0]*tq[0] + tq[1]*tq[1] + tq[2]*tq[2] + tq[3]*tq[3];
#pragma unroll
        for (int dlt = 1; dlt < 16; dlt <<= 1) {
            s  += __shfl_xor(s, dlt);
            sq += __shfl_xor(sq, dlt);
        }
        if (j == 0) {
            atomicAdd(&gnacc[(b * GG + g) * 2 + 0], s);
            atomicAdd(&gnacc[(b * GG + g) * 2 + 1], sq);
        }
    }
}

// K5: out = q + relu(gn(t)), LDS-transposed stores. grid NB*NN/64 = 256 blocks.
__global__ __launch_bounds__(256) void k_out(
    const float* __restrict__ q, const float* __restrict__ t,
    const float* __restrict__ gnacc, const float* __restrict__ gamma,
    const float* __restrict__ beta, float* __restrict__ out)
{
    __shared__ float tl[64][17], ql[64][17];
    int tid = threadIdx.x;
    int g0 = blockIdx.x * 64;          // row base (b*NN + n)
    int b = g0 >> 12;

    {
        float4 tv = *reinterpret_cast<const float4*>(t + (size_t)g0 * DD + tid * 4);
        float4 qv = *reinterpret_cast<const float4*>(q + (size_t)g0 * DD + tid * 4);
        int r = (tid * 4) >> 4, c = (tid * 4) & 15;
        tl[r][c] = tv.x; tl[r][c + 1] = tv.y; tl[r][c + 2] = tv.z; tl[r][c + 3] = tv.w;
        ql[r][c] = qv.x; ql[r][c + 1] = qv.y; ql[r][c + 2] = qv.z; ql[r][c + 3] = qv.w;
    }
    __syncthreads();

    int o = tid >> 4, n16 = tid & 15;
    int g = o >> 2;
    const float cnt = 1.0f / (4.0f * NN);
    float ms = gnacc[(b * GG + g) * 2 + 0];
    float sqs = gnacc[(b * GG + g) * 2 + 1];
    float mean = ms * cnt;
    float var = sqs * cnt - mean * mean;
    float rsig = rsqrtf(var + EPSGN);
    float ga = gamma[o], be = beta[o];

    int r0 = n16 * 4;
    float4 res;
    res.x = ql[r0    ][o] + fmaxf((tl[r0    ][o] - mean) * rsig * ga + be, 0.f);
    res.y = ql[r0 + 1][o] + fmaxf((tl[r0 + 1][o] - mean) * rsig * ga + be, 0.f);
    res.z = ql[r0 + 2][o] + fmaxf((tl[r0 + 2][o] - mean) * rsig * ga + be, 0.f);
    res.w = ql[r0 + 3][o] + fmaxf((tl[r0 + 3][o] - mean) * rsig * ga + be, 0.f);
    *reinterpret_cast<float4*>(out + ((size_t)(b * DD + o)) * NN + (g0 & (NN - 1)) + r0) = res;
}

extern "C" void kernel_launch(void* const* d_in, const int* in_sizes, int n_in,
                              void* d_out, int out_size, void* d_ws, size_t ws_size,
                              hipStream_t stream)
{
    const float* x_q      = (const float*)d_in[0];
    const float* x_kv     = (const float*)d_in[1];
    const float* xyz_q    = (const float*)d_in[2];
    const float* xyz_kv   = (const float*)d_in[3];
    const float* w_qk     = (const float*)d_in[4];
    const float* w_v      = (const float*)d_in[5];
    const float* b_v      = (const float*)d_in[6];
    const float* w_t      = (const float*)d_in[7];
    const float* b_t      = (const float*)d_in[8];
    const float* gamma    = (const float*)d_in[9];
    const float* beta     = (const float*)d_in[10];
    const float* w_pos_q  = (const float*)d_in[11];
    const float* w_pos_kv = (const float*)d_in[12];

    float* ws = (float*)d_ws;
    float* q       = ws + OFF_Q;
    float* t       = ws + OFF_T;
    float* gnacc   = ws + OFF_GN;
    unsigned short* qb  = (unsigned short*)(ws + OFF_QB);
    unsigned short* kb  = (unsigned short*)(ws + OFF_KB);
    unsigned short* vtb = (unsigned short*)(ws + OFF_VTB);
    float* out     = (float*)d_out;

    k_qkv<<<dim3(NB * NN / 64), 512, 0, stream>>>(
        x_q, x_kv, xyz_q, xyz_kv, w_qk, w_v, b_v, w_pos_q, w_pos_kv,
        q, qb, kb, vtb, gnacc);

    k_rows<<<dim3(NN / 32, NB), 512, 0, stream>>>(qb, kb);
    k_cols<<<dim3(NN / 16, NB), 256, 0, stream>>>(qb, kb);
    k_xr<<<dim3(NN / 16, NB), 256, 0, stream>>>(qb, kb, vtb, q, w_t, b_t, t, gnacc);
    k_out<<<dim3(NB * NN / 64), 256, 0, stream>>>(q, t, gnacc, gamma, beta, out);
}